// Round 2
// baseline (332.568 us; speedup 1.0000x reference)
//
#include <hip/hip_runtime.h>
#include <math.h>

#define NEG_BIG (-1e30f)

typedef __attribute__((ext_vector_type(8))) short short8;
typedef __attribute__((ext_vector_type(8))) _Float16 half8;
typedef __attribute__((ext_vector_type(4))) float floatx4;

__device__ __forceinline__ unsigned short f2bf(float x) {
    unsigned u = __float_as_uint(x);
    unsigned r = (u + 0x7fffu + ((u >> 16) & 1u)) >> 16;
    return (unsigned short)r;
}
__device__ __forceinline__ short f2h(float x) {
    _Float16 h = (_Float16)x;
    return __builtin_bit_cast(short, h);
}
__device__ __forceinline__ float h2f(short s) {
    return (float)__builtin_bit_cast(_Float16, s);
}

// ================= K1: fused prep =================
// blocks [0..1023]           : W_atom f16x2 split, [k][n] -> [n][k]
// blocks [1024..1055]        : W_bond transpose -> [h][k] bf16
// blocks [1056..1056+16B-1]  : winner = -1 (int4 stores)
// next Bmol/2 blocks         : padding mask
__global__ __launch_bounds__(256) void k_prep(
    const float* __restrict__ W, short* __restrict__ H, short* __restrict__ L,
    const float* __restrict__ Wb, short* __restrict__ Wbt,
    int* __restrict__ winner,
    const int* __restrict__ a_scope, float* __restrict__ mask_out, int Bmol)
{
    int bid = blockIdx.x;
    int tid = threadIdx.x;
    if (bid < 1024) {
        int t = bid * 256 + tid;            // 262144
        int n = t >> 9, k = t & 511;
        float x = W[(size_t)k * 512 + n];
        short h = f2h(x);
        float r = (x - h2f(h)) * 2048.0f;
        H[t] = h;
        L[t] = f2h(r);
        return;
    }
    bid -= 1024;
    if (bid < 32) {
        int t = bid * 256 + tid;            // 8192
        int h = t >> 9, k = t & 511;
        Wbt[t] = (short)f2bf(Wb[(size_t)k * 16 + h]);
        return;
    }
    bid -= 32;
    if (bid < Bmol * 16) {
        int t = bid * 256 + tid;            // int4 index
        ((int4*)winner)[t] = make_int4(-1, -1, -1, -1);
        return;
    }
    bid -= Bmol * 16;
    {
        int t = bid * 256 + tid;
        if (t < Bmol * 128) {
            int b = t >> 7, p = t & 127;
            mask_out[t] = (p >= a_scope[2 * b + 1]) ? 1.0f : 0.0f;
        }
    }
}

// ================= K2 bodies =================

// atoms GEMM: fp32 via f16x2 split, 3 MFMA products. tile 128x128, BK=32.
__device__ __forceinline__ void atoms_body(
    int abid, char* smem,
    const float* __restrict__ fA, const float* __restrict__ fAo,
    const int* __restrict__ a_scope,
    const short* __restrict__ WH, const short* __restrict__ WL,
    const float* __restrict__ bias, float* __restrict__ out, int Bmol)
{
    short* A_s = (short*)smem;               // [2][128*40]
    short* B_s = (short*)(smem + 20480);     // [2][128*40]
    int*   rs  = (int*)(smem + 40960);       // [128]

    const int tid = threadIdx.x;
    const int n0 = (abid & 3) * 128;
    const int mol = abid >> 2;

    if (tid < 128) {
        int len = a_scope[2 * mol + 1];
        rs[tid] = (tid < len) ? (a_scope[2 * mol] + tid) : -1;
    }
    const int wid = tid >> 6, lane = tid & 63;
    const int wm = (wid >> 1) * 64, wn = (wid & 1) * 64;
    const int quad = lane >> 4, l16 = lane & 15;

    floatx4 acc1[4][4], acc2[4][4];
#pragma unroll
    for (int i = 0; i < 4; i++)
#pragma unroll
        for (int j = 0; j < 4; j++) {
            acc1[i][j] = (floatx4){0.f, 0.f, 0.f, 0.f};
            acc2[i][j] = (floatx4){0.f, 0.f, 0.f, 0.f};
        }

    const int ar = tid >> 1;
    const int ak = (tid & 1) * 16;
    __syncthreads();                   // rs ready
    const int asrc = rs[ar];

    for (int k0 = 0; k0 < 512; k0 += 32) {
        float x[16];
        if (asrc >= 0) {
            int kg = k0 + ak;
            const float* p = (kg < 256) ? (fA + (size_t)asrc * 256 + kg)
                                        : (fAo + (size_t)asrc * 256 + (kg - 256));
#pragma unroll
            for (int i = 0; i < 4; i++) {
                float4 v = ((const float4*)p)[i];
                x[i * 4 + 0] = v.x; x[i * 4 + 1] = v.y;
                x[i * 4 + 2] = v.z; x[i * 4 + 3] = v.w;
            }
        } else {
#pragma unroll
            for (int i = 0; i < 16; i++) x[i] = 0.f;
        }
        size_t goff = (size_t)(n0 + ar) * 512 + k0 + ak;
        short8 bh0 = *(const short8*)(WH + goff);
        short8 bh1 = *(const short8*)(WH + goff + 8);
        short8 bl0 = *(const short8*)(WL + goff);
        short8 bl1 = *(const short8*)(WL + goff + 8);

        short8 ah0, ah1, al0, al1;
#pragma unroll
        for (int i = 0; i < 8; i++) {
            short h = f2h(x[i]);
            float r = (x[i] - h2f(h)) * 2048.0f;
            ah0[i] = h; al0[i] = f2h(r);
        }
#pragma unroll
        for (int i = 0; i < 8; i++) {
            float xx = x[8 + i];
            short h = f2h(xx);
            float r = (xx - h2f(h)) * 2048.0f;
            ah1[i] = h; al1[i] = f2h(r);
        }

        __syncthreads();
        const int abase = ar * 40 + ak;
        *(short8*)&A_s[abase] = ah0;          *(short8*)&A_s[abase + 8] = ah1;
        *(short8*)&A_s[5120 + abase] = al0;   *(short8*)&A_s[5120 + abase + 8] = al1;
        *(short8*)&B_s[abase] = bh0;          *(short8*)&B_s[abase + 8] = bh1;
        *(short8*)&B_s[5120 + abase] = bl0;   *(short8*)&B_s[5120 + abase + 8] = bl1;
        __syncthreads();

        half8 afh[4], afl[4];
#pragma unroll
        for (int ti = 0; ti < 4; ti++) {
            int off = (wm + ti * 16 + l16) * 40 + quad * 8;
            afh[ti] = *(const half8*)&A_s[off];
            afl[ti] = *(const half8*)&A_s[5120 + off];
        }
#pragma unroll
        for (int tj = 0; tj < 4; tj++) {
            int off = (wn + tj * 16 + l16) * 40 + quad * 8;
            half8 bh = *(const half8*)&B_s[off];
            half8 bl = *(const half8*)&B_s[5120 + off];
#pragma unroll
            for (int ti = 0; ti < 4; ti++) {
                acc1[ti][tj] = __builtin_amdgcn_mfma_f32_16x16x32_f16(afh[ti], bh, acc1[ti][tj], 0, 0, 0);
                acc2[ti][tj] = __builtin_amdgcn_mfma_f32_16x16x32_f16(afh[ti], bl, acc2[ti][tj], 0, 0, 0);
                acc2[ti][tj] = __builtin_amdgcn_mfma_f32_16x16x32_f16(afl[ti], bh, acc2[ti][tj], 0, 0, 0);
            }
        }
    }

#pragma unroll
    for (int tj = 0; tj < 4; tj++) {
        int n = n0 + wn + tj * 16 + l16;
        float bv = bias[n];
#pragma unroll
        for (int ti = 0; ti < 4; ti++) {
#pragma unroll
            for (int r = 0; r < 4; r++) {
                int pos = wm + ti * 16 + quad * 4 + r;
                bool valid = rs[pos] >= 0;
                float v = valid ? (acc1[ti][tj][r] + 4.8828125e-4f * acc2[ti][tj][r] + bv) : 0.f;
                out[((size_t)pos * Bmol + mol) * 512 + n] = v;
            }
        }
    }
}

// bonds GEMM: 64 bonds/block, 16 heads, K=512, bf16
__device__ __forceinline__ void bonds_body(
    int bbid, char* smem,
    const float* __restrict__ fB, const float* __restrict__ fBo,
    const short* __restrict__ Wbt, const float* __restrict__ bb_,
    float* __restrict__ bonds, int Nb)
{
    short* feat = (short*)smem;              // [64][136]
    short* wb   = (short*)(smem + 17408);    // [16][512] chunk-swizzled

    const int tid = threadIdx.x;
    const int j0 = bbid * 64;

    for (int c = tid; c < 1024; c += 256) {
        int h = c >> 6, cc = c & 63;
        short8 v = *(const short8*)(Wbt + h * 512 + cc * 8);
        *(short8*)&wb[h * 512 + (((cc + h) & 63) * 8)] = v;
    }

    const int wid = tid >> 6, lane = tid & 63;
    const int quad = lane >> 4, l16 = lane & 15;
    floatx4 acc = (floatx4){0.f, 0.f, 0.f, 0.f};

    const int fr = tid >> 2;
    const int fs = (tid & 3) * 32;
    const int j = j0 + fr;

    for (int k0 = 0; k0 < 512; k0 += 128) {
        float x[32];
        if (j < Nb) {
            const float* p = (k0 < 256) ? (fB + (size_t)j * 256 + k0 + fs)
                                        : (fBo + (size_t)j * 256 + (k0 - 256) + fs);
#pragma unroll
            for (int i = 0; i < 8; i++) {
                float4 v = ((const float4*)p)[i];
                x[i * 4 + 0] = v.x; x[i * 4 + 1] = v.y;
                x[i * 4 + 2] = v.z; x[i * 4 + 3] = v.w;
            }
        } else {
#pragma unroll
            for (int i = 0; i < 32; i++) x[i] = 0.f;
        }
        __syncthreads();
#pragma unroll
        for (int c = 0; c < 4; c++) {
            short8 s;
#pragma unroll
            for (int i = 0; i < 8; i++) s[i] = (short)f2bf(x[c * 8 + i]);
            *(short8*)&feat[fr * 136 + fs + c * 8] = s;
        }
        __syncthreads();
#pragma unroll
        for (int kk = 0; kk < 4; kk++) {
            short8 a = *(const short8*)&feat[(wid * 16 + l16) * 136 + kk * 32 + quad * 8];
            int kchunk = (k0 + kk * 32 + quad * 8) >> 3;
            short8 b = *(const short8*)&wb[l16 * 512 + (((kchunk + l16) & 63) * 8)];
            acc = __builtin_amdgcn_mfma_f32_16x16x32_bf16(a, b, acc, 0, 0, 0);
        }
    }
    float bv = bb_[l16];
#pragma unroll
    for (int r = 0; r < 4; r++) {
        int jj = j0 + wid * 16 + quad * 4 + r;
        if (jj < Nb) bonds[(size_t)jj * 16 + l16] = acc[r] + bv;
    }
}

// out_ap pattern fill: (p2 >= len) ? NEG_BIG : 0, 64 B per thread
__device__ __forceinline__ void fill_body(
    int fbid, const int* __restrict__ a_scope, float* __restrict__ out_ap)
{
    int f = fbid * 256 + threadIdx.x;        // 16-float chunk id
    int r = f >> 3;                          // row: b*2048 + h*128 + p1
    int b = r >> 11;
    int p2b = (f & 7) * 16;
    int len = a_scope[2 * b + 1];
    float4* dst = (float4*)(out_ap + (size_t)f * 16);
#pragma unroll
    for (int c = 0; c < 4; c++) {
        float4 v;
        v.x = (p2b + c * 4 + 0 >= len) ? NEG_BIG : 0.f;
        v.y = (p2b + c * 4 + 1 >= len) ? NEG_BIG : 0.f;
        v.z = (p2b + c * 4 + 2 >= len) ? NEG_BIG : 0.f;
        v.w = (p2b + c * 4 + 3 >= len) ? NEG_BIG : 0.f;
        dst[c] = v;
    }
}

// scatter: last-update-wins via atomicMax on bond index
__device__ __forceinline__ void scatter_body(
    int sbid, char* smem,
    const int* __restrict__ b2a, const int* __restrict__ b2revb,
    const int* __restrict__ b_scope, int* __restrict__ winner,
    int Nb, int Bmol)
{
    int* sb = (int*)smem;
    int tid = threadIdx.x;
    if (tid < Bmol) sb[tid] = b_scope[2 * tid];
    __syncthreads();
    int j = sbid * 256 + tid;
    if (j >= Nb) return;
    int lo = 0, hi = Bmol;
    while (lo < hi) { int mid = (lo + hi) >> 1; if (sb[mid] <= j) lo = mid + 1; else hi = mid; }
    int mol = lo - 1; if (mol < 0) mol = 0;
    int p2 = b2a[j];
    int p1 = b2a[b2revb[j]];
    atomicMax(&winner[mol * 16384 + p1 * 128 + p2], j);
}

// ================= K2: fused main =================
__global__ __launch_bounds__(256, 2) void k_main(
    const float* __restrict__ fA, const float* __restrict__ fAo,
    const float* __restrict__ fB, const float* __restrict__ fBo,
    const int* __restrict__ b2a, const int* __restrict__ b2revb,
    const int* __restrict__ a_scope, const int* __restrict__ b_scope,
    const short* __restrict__ WH, const short* __restrict__ WL,
    const short* __restrict__ Wbt,
    const float* __restrict__ b_atom, const float* __restrict__ b_bond,
    float* __restrict__ out_emb, float* __restrict__ out_ap,
    float* __restrict__ bonds_ws, int* __restrict__ winner,
    int Bmol, int Nb, int nAtomsB, int nBondsB, int nFillB)
{
    __shared__ char smem[41472];
    int bid = blockIdx.x;
    if (bid < nAtomsB) {
        atoms_body(bid, smem, fA, fAo, a_scope, WH, WL, b_atom, out_emb, Bmol);
        return;
    }
    bid -= nAtomsB;
    if (bid < nBondsB) {
        bonds_body(bid, smem, fB, fBo, Wbt, b_bond, bonds_ws, Nb);
        return;
    }
    bid -= nBondsB;
    if (bid < nFillB) {
        fill_body(bid, a_scope, out_ap);
        return;
    }
    bid -= nFillB;
    scatter_body(bid, smem, b2a, b2revb, b_scope, winner, Nb, Bmol);
}

// ================= K3: commit winner bonds into out_ap =================
__global__ __launch_bounds__(256) void k_commit(
    const int* __restrict__ b2a, const int* __restrict__ b2revb,
    const int* __restrict__ b_scope, const int* __restrict__ a_scope,
    const int* __restrict__ winner, const float* __restrict__ bonds,
    float* __restrict__ out_ap, int Nb, int Bmol)
{
    __shared__ int sb[128];
    int tid = threadIdx.x;
    if (tid < Bmol) sb[tid] = b_scope[2 * tid];
    __syncthreads();
    int j = blockIdx.x * 256 + tid;
    if (j >= Nb) return;
    int lo = 0, hi = Bmol;
    while (lo < hi) { int mid = (lo + hi) >> 1; if (sb[mid] <= j) lo = mid + 1; else hi = mid; }
    int mol = lo - 1; if (mol < 0) mol = 0;
    int p2 = b2a[j];
    int p1 = b2a[b2revb[j]];
    int cell = mol * 16384 + p1 * 128 + p2;
    if (winner[cell] != j) return;
    if (p2 >= a_scope[2 * mol + 1]) return;   // reference masks these cells after scatter
    const float4* src = (const float4*)(bonds + (size_t)j * 16);
    float4 v0 = src[0], v1 = src[1], v2 = src[2], v3 = src[3];
    float vals[16] = {v0.x, v0.y, v0.z, v0.w, v1.x, v1.y, v1.z, v1.w,
                      v2.x, v2.y, v2.z, v2.w, v3.x, v3.y, v3.z, v3.w};
    float* dst = out_ap + ((size_t)mol * 16 * 128 + p1) * 128 + p2;
#pragma unroll
    for (int h = 0; h < 16; h++) dst[(size_t)h * 16384] = vals[h];
}

extern "C" void kernel_launch(void* const* d_in, const int* in_sizes, int n_in,
                              void* d_out, int out_size, void* d_ws, size_t ws_size,
                              hipStream_t stream)
{
    const float* f_atoms     = (const float*)d_in[0];
    const float* f_bonds     = (const float*)d_in[1];
    const float* f_atoms_out = (const float*)d_in[2];
    const float* f_bonds_out = (const float*)d_in[3];
    const int*   b2a         = (const int*)d_in[4];
    const int*   b2revb      = (const int*)d_in[5];
    const int*   a_scope     = (const int*)d_in[6];
    const int*   b_scope     = (const int*)d_in[7];
    const float* W_atom      = (const float*)d_in[9];
    const float* b_atom      = (const float*)d_in[10];
    const float* W_bond      = (const float*)d_in[11];
    const float* b_bond      = (const float*)d_in[12];

    const int Bmol = in_sizes[6] / 2;   // 128
    const int Nb   = in_sizes[4];

    char* ws = (char*)d_ws;
    size_t off = 0;
    float* bonds_ws = (float*)(ws + off); off += ((size_t)Nb * 16 * 4 + 255) & ~(size_t)255;
    int*   winner   = (int*)(ws + off);   off += (size_t)Bmol * 16384 * 4;
    short* WH       = (short*)(ws + off); off += 512 * 512 * 2;
    short* WL       = (short*)(ws + off); off += 512 * 512 * 2;
    short* Wbt      = (short*)(ws + off); off += 16 * 512 * 2;

    float* out_emb  = (float*)d_out;                                // (128, B, 512)
    float* out_ap   = out_emb + (size_t)128 * Bmol * 512;           // (B, 16, 128, 128)
    float* out_mask = out_ap + (size_t)Bmol * 16 * 128 * 128;       // (B, 128)

    // K1: prep (Wa split | Wb transpose | winner init | mask)
    const int prepB = 1024 + 32 + Bmol * 16 + (Bmol * 128 + 255) / 256;
    hipLaunchKernelGGL(k_prep, dim3(prepB), dim3(256), 0, stream,
                       W_atom, WH, WL, W_bond, Wbt, winner, a_scope, out_mask, Bmol);

    // K2: atoms GEMM | bonds GEMM | out_ap fill | scatter — concurrent
    const int nAtomsB = 4 * Bmol;
    const int nBondsB = (Nb + 63) / 64;
    const int nFillB  = Bmol * 64;          // 64B/thread over B*16*128*128 floats
    const int nScatB  = (Nb + 255) / 256;
    hipLaunchKernelGGL(k_main, dim3(nAtomsB + nBondsB + nFillB + nScatB), dim3(256), 0, stream,
                       f_atoms, f_atoms_out, f_bonds, f_bonds_out,
                       b2a, b2revb, a_scope, b_scope,
                       WH, WL, Wbt, b_atom, b_bond,
                       out_emb, out_ap, bonds_ws, winner,
                       Bmol, Nb, nAtomsB, nBondsB, nFillB);

    // K3: commit winning bonds
    hipLaunchKernelGGL(k_commit, dim3(nScatB), dim3(256), 0, stream,
                       b2a, b2revb, b_scope, a_scope, winner, bonds_ws, out_ap, Nb, Bmol);
}